// Round 4
// baseline (225.666 us; speedup 1.0000x reference)
//
#include <hip/hip_runtime.h>
#include <math.h>

#define R_NODES 1152
#define DIGITS 10
#define OUT_CH 16
#define IN_CH 8
#define BATCH 256
#define COLS 160            // DIGITS*OUT_CH
#define W_PER_R 1280        // DIGITS*OUT_CH*IN_CH
#define NSPLIT 72           // K-split: 16 r-rows per block
#define YBLK 8              // batch blocks (32 b each)
#define AB_STRIDE (YBLK * R_NODES * DIGITS)   // 92160 floats per ab iteration-buffer

// ---------- s partials + fused per-block softmax ----------
// grid (72, 8): blockIdx.x = 16-row slice, blockIdx.y = 32-batch block.
// 256 threads = 16 colgroups (g) x 16 b-subgroups (bs: 2 b each).
// W tile staged in double-buffered LDS chunks of 4 rows; next chunk's global
// loads are issued into registers BEFORE computing the current chunk (latency
// hidden under 640 FMA/thread), ds_write after, ONE barrier per chunk.
// c (softmax of summed ab partials) computed per block into LDS (nbuf==0 -> 0.1).
__global__ __launch_bounds__(256) void k_s(
    const float* __restrict__ u,      // [B][R][8]
    const float* __restrict__ W,      // [R][10][16][8]
    const float* __restrict__ ab,     // [nbuf][YBLK][R][10] agreement partials
    float* __restrict__ part,         // [NSPLIT][B][160]
    float* __restrict__ sq,
    int nbuf)
{
    __shared__ float wt[2][4 * 1600];   // 2 buffers x (4 rows x 160 cols x pad-stride 10)
    __shared__ float cs[160];           // c for this block's 16 rows

    const int split = blockIdx.x;
    const int b0 = blockIdx.y * 32;
    const int t = threadIdx.x;
    const int g = t & 15;
    const int bs = t >> 4;
    const int r0 = split * 16;

    if (split == 0 && blockIdx.y == 0 && t == 0) *sq = 0.f;

    // ---- c for rows r0..r0+15 ----
    if (nbuf == 0) {
        if (t < 160) cs[t] = 0.1f;
    } else {
        if (t < 160) {
            int r_l = t / 10, d = t - r_l * 10;
            const float* p0 = ab + (size_t)(r0 + r_l) * DIGITS + d;
            float a = 0.f;
            for (int bu = 0; bu < nbuf; ++bu)
#pragma unroll
                for (int yy = 0; yy < YBLK; ++yy)
                    a += p0[(size_t)bu * AB_STRIDE + (size_t)yy * (R_NODES * DIGITS)];
            cs[t] = a;
        }
        __syncthreads();
        if (t < 16) {
            float e[DIGITS];
            float m = -1e30f;
#pragma unroll
            for (int d = 0; d < DIGITS; ++d) m = fmaxf(m, cs[t*10 + d]);
            float ssum = 0.f;
#pragma unroll
            for (int d = 0; d < DIGITS; ++d) { e[d] = expf(cs[t*10 + d] - m); ssum += e[d]; }
            float inv = 1.f / ssum;
#pragma unroll
            for (int d = 0; d < DIGITS; ++d) cs[t*10 + d] = e[d] * inv;
        }
    }

    float acc[2][10];
#pragma unroll
    for (int jj = 0; jj < 2; ++jj)
#pragma unroll
        for (int j = 0; j < 10; ++j) acc[jj][j] = 0.f;

    // per-thread constant decode of the 5 staged float4s per chunk
    int soff[5], ccol[5];
#pragma unroll
    for (int p = 0; p < 5; ++p) {
        int e4 = t + p * 256, e = e4 * 4;
        int r_l = e4 / 320;               // 320 float4 per row
        int rem = e - r_l * W_PER_R;
        int col = rem >> 3, i0 = e & 7;   // i0 in {0,4}
        soff[p] = r_l * 1600 + col * 10 + i0;
        ccol[p] = r_l * 10 + (col >> 4);
    }

    float4 wr[5];
    // prologue: load + write chunk 0
    {
        const float4* Wg = (const float4*)(W + (size_t)r0 * W_PER_R);
#pragma unroll
        for (int p = 0; p < 5; ++p) wr[p] = Wg[t + p * 256];
    }
    __syncthreads();                      // cs ready
#pragma unroll
    for (int p = 0; p < 5; ++p) {
        float cv = cs[ccol[p]];
        float2* dst = (float2*)&wt[0][soff[p]];
        dst[0] = make_float2(wr[p].x * cv, wr[p].y * cv);
        dst[1] = make_float2(wr[p].z * cv, wr[p].w * cv);
    }
    __syncthreads();

    for (int ch = 0; ch < 4; ++ch) {
        const int buf = ch & 1;
        if (ch < 3) {   // issue next chunk's global loads (latency hides under compute)
            const float4* Wg = (const float4*)(W + (size_t)(r0 + (ch + 1) * 4) * W_PER_R);
#pragma unroll
            for (int p = 0; p < 5; ++p) wr[p] = Wg[t + p * 256];
        }
        // ---- compute chunk ch (rows r0+ch*4 .. +4) ----
#pragma unroll
        for (int r_l = 0; r_l < 4; ++r_l) {
            float uu[2][8];
#pragma unroll
            for (int jj = 0; jj < 2; ++jj) {
                const float* up = u + (size_t)(b0 + bs*2 + jj) * (R_NODES*IN_CH)
                                    + (size_t)(r0 + ch*4 + r_l) * IN_CH;
                float4 a0 = *(const float4*)up;
                float4 a1 = *(const float4*)(up + 4);
                uu[jj][0]=a0.x; uu[jj][1]=a0.y; uu[jj][2]=a0.z; uu[jj][3]=a0.w;
                uu[jj][4]=a1.x; uu[jj][5]=a1.y; uu[jj][6]=a1.z; uu[jj][7]=a1.w;
            }
            const float* wrow = &wt[buf][r_l*1600 + g*100];
#pragma unroll
            for (int j = 0; j < 10; ++j) {
                const float2* wp = (const float2*)(wrow + j*10);
                float2 w01 = wp[0], w23 = wp[1], w45 = wp[2], w67 = wp[3];
#pragma unroll
                for (int jj = 0; jj < 2; ++jj) {
                    float a = acc[jj][j];
                    a = fmaf(w01.x, uu[jj][0], a);
                    a = fmaf(w01.y, uu[jj][1], a);
                    a = fmaf(w23.x, uu[jj][2], a);
                    a = fmaf(w23.y, uu[jj][3], a);
                    a = fmaf(w45.x, uu[jj][4], a);
                    a = fmaf(w45.y, uu[jj][5], a);
                    a = fmaf(w67.x, uu[jj][6], a);
                    a = fmaf(w67.y, uu[jj][7], a);
                    acc[jj][j] = a;
                }
            }
        }
        if (ch < 3) {   // write next chunk into the other buffer, single barrier
#pragma unroll
            for (int p = 0; p < 5; ++p) {
                float cv = cs[(ch + 1) * 40 + ccol[p]];
                float2* dst = (float2*)&wt[buf ^ 1][soff[p]];
                dst[0] = make_float2(wr[p].x * cv, wr[p].y * cv);
                dst[1] = make_float2(wr[p].z * cv, wr[p].w * cv);
            }
            __syncthreads();
        }
    }

    // deterministic partial write (no atomics)
    float* pp = part + (size_t)split * (BATCH*COLS) + (size_t)b0 * COLS;
#pragma unroll
    for (int jj = 0; jj < 2; ++jj) {
        float* row = pp + (size_t)(bs*2 + jj) * COLS + g * 10;
#pragma unroll
        for (int j = 0; j < 10; ++j) row[j] = acc[jj][j];
    }
}

// ---------- reduce partials -> s ; accumulate global sum of squares ----------
__global__ void k_sq(const float* __restrict__ part,
                     float* __restrict__ s,
                     float* __restrict__ sq, int nsplit)
{
    int e = blockIdx.x * 256 + threadIdx.x;   // grid = 160 blocks, exact
    float v = 0.f;
    for (int sp = 0; sp < nsplit; ++sp)
        v += part[(size_t)sp * (BATCH*COLS) + e];
    s[e] = v;
    float x = v * v;
#pragma unroll
    for (int off = 32; off > 0; off >>= 1)
        x += __shfl_down(x, off, 64);
    __shared__ float red[4];
    int w = threadIdx.x >> 6;
    if ((threadIdx.x & 63) == 0) red[w] = x;
    __syncthreads();
    if (threadIdx.x == 0)
        atomicAdd(sq, red[0] + red[1] + red[2] + red[3]);
}

// ---------- agreement partials: ab[y][r,d] = scale * sum_{b in y,o} u_hat*s ----------
// grid (144, 8): 8 r-rows x 32 batches per block. 256 thr = 8 r_l x 32 lanes.
// s-tile [32][160] and u-tile [32][64] staged in LDS (28.5 KB) -> inner loop is
// pure LDS+FMA. s-reads: 32 distinct banks + half-wave broadcast; u-reads: broadcast.
__global__ __launch_bounds__(256) void k_a(
    const float* __restrict__ u,
    const float* __restrict__ W,
    const float* __restrict__ s,
    const float* __restrict__ sq,
    float* __restrict__ ab)
{
    __shared__ float st[32 * COLS];   // 20.5 KB
    __shared__ float ut[32 * 64];     // 8 KB
    const int t = threadIdx.x;
    const int rblk = blockIdx.x;
    const int r = rblk * 8 + (t >> 5);
    const int tt = t & 31;
    const int bstart = blockIdx.y * 32;

    // stage s (coalesced float4)
    {
        const float4* sp = (const float4*)(s + (size_t)bstart * COLS);
#pragma unroll
        for (int p = 0; p < 5; ++p) ((float4*)st)[t + p * 256] = sp[t + p * 256];
    }
    // stage u: u[bstart+b][rblk*8 .. +8][8] = 64 contiguous floats per b
#pragma unroll
    for (int p = 0; p < 2; ++p) {
        int idx = t + p * 256;
        int b = idx >> 4, q = idx & 15;
        ((float4*)ut)[idx] =
            ((const float4*)(u + (size_t)(bstart + b) * (R_NODES*IN_CH) + (size_t)rblk * 64))[q];
    }

    float wreg[5][8];
#pragma unroll
    for (int k = 0; k < 5; ++k) {
        const float4* wp = (const float4*)(W + (size_t)r * W_PER_R + (size_t)(tt + 32*k) * IN_CH);
        float4 w0 = wp[0], w1 = wp[1];
        wreg[k][0]=w0.x; wreg[k][1]=w0.y; wreg[k][2]=w0.z; wreg[k][3]=w0.w;
        wreg[k][4]=w1.x; wreg[k][5]=w1.y; wreg[k][6]=w1.z; wreg[k][7]=w1.w;
    }
    __syncthreads();

    float acc[5] = {0.f, 0.f, 0.f, 0.f, 0.f};
#pragma unroll 2
    for (int b = 0; b < 32; ++b) {
        const float* ub = &ut[b * 64 + (t >> 5) * 8];
        float4 a0 = *(const float4*)ub;
        float4 a1 = *(const float4*)(ub + 4);
        const float* sb = &st[b * COLS];
#pragma unroll
        for (int k = 0; k < 5; ++k) {
            float vv = sb[tt + 32*k];
            float uh;
            uh = wreg[k][0] * a0.x;
            uh = fmaf(wreg[k][1], a0.y, uh);
            uh = fmaf(wreg[k][2], a0.z, uh);
            uh = fmaf(wreg[k][3], a0.w, uh);
            uh = fmaf(wreg[k][4], a1.x, uh);
            uh = fmaf(wreg[k][5], a1.y, uh);
            uh = fmaf(wreg[k][6], a1.z, uh);
            uh = fmaf(wreg[k][7], a1.w, uh);
            acc[k] = fmaf(uh, vv, acc[k]);
        }
    }
    float q = *sq;
    float scale = sqrtf(q) / (1.f + q);
    float* abp = ab + (size_t)blockIdx.y * (R_NODES * DIGITS) + r * DIGITS;
#pragma unroll
    for (int k = 0; k < 5; ++k) {
        float x = acc[k] * scale;
        x += __shfl_xor(x, 1, 64);
        x += __shfl_xor(x, 2, 64);
        x += __shfl_xor(x, 4, 64);
        x += __shfl_xor(x, 8, 64);
        if ((tt & 15) == 0) {
            int d = (tt >> 4) + 2*k;
            abp[d] = x;
        }
    }
}

// ---------- final output: v = s * sqrt(sq)/(1+sq) ----------
__global__ void k_scale(const float* __restrict__ s,
                        const float* __restrict__ sq,
                        float* __restrict__ out)
{
    int e = blockIdx.x * 256 + threadIdx.x;
    float q = *sq;
    float scale = sqrtf(q) / (1.f + q);
    out[e] = s[e] * scale;
}

extern "C" void kernel_launch(void* const* d_in, const int* in_sizes, int n_in,
                              void* d_out, int out_size, void* d_ws, size_t ws_size,
                              hipStream_t stream)
{
    const float* u = (const float*)d_in[0];   // (256, 1152, 8)
    const float* W = (const float*)d_in[1];   // (1, 1152, 10, 16, 8)
    float* out = (float*)d_out;               // (256, 10, 16)
    float* ws = (float*)d_ws;

    float* s    = ws;                          // 40960 floats
    float* sq   = ws + 40960;                  // 1 (padded to 64)
    float* ab   = ws + 41024;                  // 2 * 92160
    float* part = ws + 41024 + 2 * AB_STRIDE;  // 72 * 40960  (~11.8 MB; ws is 256 MiB)

    for (int it = 0; it < 3; ++it) {
        k_s<<<dim3(NSPLIT, YBLK), dim3(256), 0, stream>>>(u, W, ab, part, sq, it);
        k_sq<<<dim3(BATCH * COLS / 256), dim3(256), 0, stream>>>(part, s, sq, NSPLIT);
        if (it < 2)
            k_a<<<dim3(R_NODES / 8, YBLK), dim3(256), 0, stream>>>(u, W, s, sq,
                                                                   ab + (size_t)it * AB_STRIDE);
        else
            k_scale<<<dim3(BATCH * COLS / 256), dim3(256), 0, stream>>>(s, sq, out);
    }
}

// Round 5
// 186.589 us; speedup vs baseline: 1.2094x; 1.2094x over previous
//
#include <hip/hip_runtime.h>
#include <math.h>

#define R_NODES 1152
#define DIGITS 10
#define OUT_CH 16
#define IN_CH 8
#define BATCH 256
#define COLS 160            // DIGITS*OUT_CH
#define W_PER_R 1280        // DIGITS*OUT_CH*IN_CH
#define NSPLIT 72           // K-split: 16 r-rows per block
#define YB_S 16             // k_s batch blocks (16 b each)
#define YBLK 8              // k_a batch blocks (32 b each)
#define AB_STRIDE (YBLK * R_NODES * DIGITS)   // 92160 floats per ab iteration-buffer

// ---------- s partials + fused per-block softmax ----------
// grid (72, 16): blockIdx.x = 16-row slice, blockIdx.y = 16-batch block.
// 256 threads = 16 colgroups (g, 10 cols each) x 16 batches (bs, 1 b each).
// W staged in single-buffered 4-row LDS chunks (25.6 KB): issue chunk loads,
// barrier (prev readers done / cs ready), ds_write, barrier, compute.
// wr[] live only in the staging window -> low VGPR; latency hidden by ~5
// resident blocks/CU. c (softmax of summed ab partials) per block into LDS.
__global__ __launch_bounds__(256) void k_s(
    const float* __restrict__ u,      // [B][R][8]
    const float* __restrict__ W,      // [R][10][16][8]
    const float* __restrict__ ab,     // [nbuf][YBLK][R][10] agreement partials
    float* __restrict__ part,         // [NSPLIT][B][160]
    float* __restrict__ sq,
    int nbuf)
{
    __shared__ float wt[4 * 1600];      // 4 rows x 160 cols x pad-stride 10
    __shared__ float cs[160];           // c for this block's 16 rows

    const int split = blockIdx.x;
    const int b = blockIdx.y * YB_S + (threadIdx.x >> 4);
    const int t = threadIdx.x;
    const int g = t & 15;
    const int r0 = split * 16;

    if (split == 0 && blockIdx.y == 0 && t == 0) *sq = 0.f;

    // ---- c for rows r0..r0+15 ----
    if (nbuf == 0) {
        if (t < 160) cs[t] = 0.1f;
        // visibility guaranteed by the barrier inside the ch=0 staging below
    } else {
        if (t < 160) {
            int r_l = t / 10, d = t - r_l * 10;
            const float* p0 = ab + (size_t)(r0 + r_l) * DIGITS + d;
            float a = 0.f;
            for (int bu = 0; bu < nbuf; ++bu)
#pragma unroll
                for (int yy = 0; yy < YBLK; ++yy)
                    a += p0[(size_t)bu * AB_STRIDE + (size_t)yy * (R_NODES * DIGITS)];
            cs[t] = a;
        }
        __syncthreads();
        if (t < 16) {
            float e[DIGITS];
            float m = -1e30f;
#pragma unroll
            for (int d = 0; d < DIGITS; ++d) m = fmaxf(m, cs[t*10 + d]);
            float ssum = 0.f;
#pragma unroll
            for (int d = 0; d < DIGITS; ++d) { e[d] = expf(cs[t*10 + d] - m); ssum += e[d]; }
            float inv = 1.f / ssum;
#pragma unroll
            for (int d = 0; d < DIGITS; ++d) cs[t*10 + d] = e[d] * inv;
        }
    }

    float acc[10];
#pragma unroll
    for (int j = 0; j < 10; ++j) acc[j] = 0.f;

    // per-thread constant decode of the 5 staged float4s per 4-row chunk
    int soff[5], ccol[5];
#pragma unroll
    for (int p = 0; p < 5; ++p) {
        int e4 = t + p * 256, e = e4 * 4;
        int r_l = e4 / 320;               // 320 float4 per row
        int rem = e - r_l * W_PER_R;
        int col = rem >> 3, i0 = e & 7;   // i0 in {0,4}
        soff[p] = r_l * 1600 + col * 10 + i0;
        ccol[p] = r_l * 10 + (col >> 4);
    }

    const float* up0 = u + (size_t)b * (R_NODES * IN_CH) + (size_t)r0 * IN_CH;

    for (int ch = 0; ch < 4; ++ch) {
        // issue this chunk's global loads (overlap other warps' compute)
        float4 wr[5];
        const float4* Wg = (const float4*)(W + (size_t)(r0 + ch * 4) * W_PER_R);
#pragma unroll
        for (int p = 0; p < 5; ++p) wr[p] = Wg[t + p * 256];
        __syncthreads();   // previous chunk's readers done; cs ready (ch==0)
#pragma unroll
        for (int p = 0; p < 5; ++p) {
            float cv = cs[ch * 40 + ccol[p]];
            float2* dst = (float2*)&wt[soff[p]];
            dst[0] = make_float2(wr[p].x * cv, wr[p].y * cv);
            dst[1] = make_float2(wr[p].z * cv, wr[p].w * cv);
        }
        __syncthreads();
        // ---- compute chunk ch (rows r0+ch*4 .. +4) ----
#pragma unroll
        for (int r_l = 0; r_l < 4; ++r_l) {
            const float* up = up0 + (size_t)(ch * 4 + r_l) * IN_CH;
            float4 a0 = *(const float4*)up;
            float4 a1 = *(const float4*)(up + 4);
            const float* wrow = &wt[r_l * 1600 + g * 100];
#pragma unroll
            for (int j = 0; j < 10; ++j) {
                const float2* wp = (const float2*)(wrow + j * 10);
                float2 w01 = wp[0], w23 = wp[1], w45 = wp[2], w67 = wp[3];
                float a = acc[j];
                a = fmaf(w01.x, a0.x, a);
                a = fmaf(w01.y, a0.y, a);
                a = fmaf(w23.x, a0.z, a);
                a = fmaf(w23.y, a0.w, a);
                a = fmaf(w45.x, a1.x, a);
                a = fmaf(w45.y, a1.y, a);
                a = fmaf(w67.x, a1.z, a);
                a = fmaf(w67.y, a1.w, a);
                acc[j] = a;
            }
        }
    }

    // deterministic partial write (no atomics)
    float* row = part + (size_t)split * (BATCH * COLS) + (size_t)b * COLS + g * 10;
#pragma unroll
    for (int j = 0; j < 10; ++j) row[j] = acc[j];
}

// ---------- reduce partials -> s ; accumulate global sum of squares ----------
// grid (640): 64 elements per block, 256 threads = 64 elems x 4-way split over
// the 72 partial buffers, LDS tree for the 4-way, wave-shuffle for sq.
__global__ void k_sq(const float* __restrict__ part,
                     float* __restrict__ s,
                     float* __restrict__ sq)
{
    const int t = threadIdx.x;
    const int e0 = blockIdx.x * 64;
    const int el = t & 63, q = t >> 6;
    float v = 0.f;
    for (int sp = q; sp < NSPLIT; sp += 4)
        v += part[(size_t)sp * (BATCH * COLS) + e0 + el];
    __shared__ float red[256];
    red[t] = v;
    __syncthreads();
    if (t < 64) {
        float vv = red[t] + red[t + 64] + red[t + 128] + red[t + 192];
        s[e0 + t] = vv;
        float x = vv * vv;
#pragma unroll
        for (int off = 32; off > 0; off >>= 1)
            x += __shfl_down(x, off, 64);
        if (t == 0) atomicAdd(sq, x);
    }
}

// ---------- agreement partials: ab[y][r,d] = scale * sum_{b in y,o} u_hat*s ----------
// grid (144, 8): 8 r-rows x 32 batches per block. 256 thr = 8 r_l x 32 lanes.
// s-tile [32][160] and u-tile [32][64] staged in LDS -> inner loop pure LDS+FMA.
__global__ __launch_bounds__(256) void k_a(
    const float* __restrict__ u,
    const float* __restrict__ W,
    const float* __restrict__ s,
    const float* __restrict__ sq,
    float* __restrict__ ab)
{
    __shared__ float st[32 * COLS];   // 20.5 KB
    __shared__ float ut[32 * 64];     // 8 KB
    const int t = threadIdx.x;
    const int rblk = blockIdx.x;
    const int r = rblk * 8 + (t >> 5);
    const int tt = t & 31;
    const int bstart = blockIdx.y * 32;

    {
        const float4* sp = (const float4*)(s + (size_t)bstart * COLS);
#pragma unroll
        for (int p = 0; p < 5; ++p) ((float4*)st)[t + p * 256] = sp[t + p * 256];
    }
#pragma unroll
    for (int p = 0; p < 2; ++p) {
        int idx = t + p * 256;
        int bb = idx >> 4, qq = idx & 15;
        ((float4*)ut)[idx] =
            ((const float4*)(u + (size_t)(bstart + bb) * (R_NODES*IN_CH) + (size_t)rblk * 64))[qq];
    }

    float wreg[5][8];
#pragma unroll
    for (int k = 0; k < 5; ++k) {
        const float4* wp = (const float4*)(W + (size_t)r * W_PER_R + (size_t)(tt + 32*k) * IN_CH);
        float4 w0 = wp[0], w1 = wp[1];
        wreg[k][0]=w0.x; wreg[k][1]=w0.y; wreg[k][2]=w0.z; wreg[k][3]=w0.w;
        wreg[k][4]=w1.x; wreg[k][5]=w1.y; wreg[k][6]=w1.z; wreg[k][7]=w1.w;
    }
    __syncthreads();

    float acc[5] = {0.f, 0.f, 0.f, 0.f, 0.f};
#pragma unroll 2
    for (int b = 0; b < 32; ++b) {
        const float* ub = &ut[b * 64 + (t >> 5) * 8];
        float4 a0 = *(const float4*)ub;
        float4 a1 = *(const float4*)(ub + 4);
        const float* sb = &st[b * COLS];
#pragma unroll
        for (int k = 0; k < 5; ++k) {
            float vv = sb[tt + 32*k];
            float uh;
            uh = wreg[k][0] * a0.x;
            uh = fmaf(wreg[k][1], a0.y, uh);
            uh = fmaf(wreg[k][2], a0.z, uh);
            uh = fmaf(wreg[k][3], a0.w, uh);
            uh = fmaf(wreg[k][4], a1.x, uh);
            uh = fmaf(wreg[k][5], a1.y, uh);
            uh = fmaf(wreg[k][6], a1.z, uh);
            uh = fmaf(wreg[k][7], a1.w, uh);
            acc[k] = fmaf(uh, vv, acc[k]);
        }
    }
    float q = *sq;
    float scale = sqrtf(q) / (1.f + q);
    float* abp = ab + (size_t)blockIdx.y * (R_NODES * DIGITS) + r * DIGITS;
#pragma unroll
    for (int k = 0; k < 5; ++k) {
        float x = acc[k] * scale;
        x += __shfl_xor(x, 1, 64);
        x += __shfl_xor(x, 2, 64);
        x += __shfl_xor(x, 4, 64);
        x += __shfl_xor(x, 8, 64);
        if ((tt & 15) == 0) {
            int d = (tt >> 4) + 2*k;
            abp[d] = x;
        }
    }
}

// ---------- final output: v = s * sqrt(sq)/(1+sq) ----------
__global__ void k_scale(const float* __restrict__ s,
                        const float* __restrict__ sq,
                        float* __restrict__ out)
{
    int e = blockIdx.x * 256 + threadIdx.x;
    float q = *sq;
    float scale = sqrtf(q) / (1.f + q);
    out[e] = s[e] * scale;
}

extern "C" void kernel_launch(void* const* d_in, const int* in_sizes, int n_in,
                              void* d_out, int out_size, void* d_ws, size_t ws_size,
                              hipStream_t stream)
{
    const float* u = (const float*)d_in[0];   // (256, 1152, 8)
    const float* W = (const float*)d_in[1];   // (1, 1152, 10, 16, 8)
    float* out = (float*)d_out;               // (256, 10, 16)
    float* ws = (float*)d_ws;

    float* s    = ws;                          // 40960 floats
    float* sq   = ws + 40960;                  // 1 (padded to 64)
    float* ab   = ws + 41024;                  // 2 * 92160
    float* part = ws + 41024 + 2 * AB_STRIDE;  // 72 * 40960  (~11.8 MB; ws is 256 MiB)

    for (int it = 0; it < 3; ++it) {
        k_s<<<dim3(NSPLIT, BATCH / YB_S), dim3(256), 0, stream>>>(u, W, ab, part, sq, it);
        k_sq<<<dim3(BATCH * COLS / 64), dim3(256), 0, stream>>>(part, s, sq);
        if (it < 2)
            k_a<<<dim3(R_NODES / 8, YBLK), dim3(256), 0, stream>>>(u, W, s, sq,
                                                                   ab + (size_t)it * AB_STRIDE);
        else
            k_scale<<<dim3(BATCH * COLS / 256), dim3(256), 0, stream>>>(s, sq, out);
    }
}

// Round 6
// 166.258 us; speedup vs baseline: 1.3573x; 1.1223x over previous
//
#include <hip/hip_runtime.h>
#include <math.h>

#define R_NODES 1152
#define DIGITS 10
#define OUT_CH 16
#define IN_CH 8
#define BATCH 256
#define COLS 160            // DIGITS*OUT_CH
#define W_PER_R 1280        // DIGITS*OUT_CH*IN_CH
#define NSPLIT 144          // K-split: 8 r-rows per block
#define YB_S 8              // k_s batch blocks (32 b each)
#define YBLK 8              // k_a batch blocks (32 b each)
#define AB_STRIDE (YBLK * R_NODES * DIGITS)   // 92160 floats per ab iteration-buffer

// ---------- s partials + fused per-block softmax ----------
// grid (144, 8): blockIdx.x = 8-row slice, blockIdx.y = 32-batch block.
// 256 threads = 16 colgroups (g, 10 cols each) x 16 batch-pairs (bs, jj=2).
// W for ALL 8 rows staged ONCE into 51.2 KB LDS (3 blocks/CU): issue 10 f4
// global loads -> cs logits (overlaps load latency) -> softmax -> scale+write
// -> ONE compute phase (no more chunk barriers). jj=2 halves W-LDS reads.
__global__ __launch_bounds__(256) void k_s(
    const float* __restrict__ u,      // [B][R][8]
    const float* __restrict__ W,      // [R][10][16][8]
    const float* __restrict__ ab,     // [nbuf][YBLK][R][10] agreement partials
    float* __restrict__ part,         // [NSPLIT][B][160]
    float* __restrict__ sq,
    int nbuf)
{
    __shared__ float wt[8 * 1600];      // 8 rows x 160 cols x pad-stride 10 = 51.2 KB
    __shared__ float cs[80];            // c for this block's 8 rows

    const int split = blockIdx.x;
    const int b0 = blockIdx.y * 32;
    const int t = threadIdx.x;
    const int g = t & 15;
    const int bs = t >> 4;
    const int r0 = split * 8;

    if (split == 0 && blockIdx.y == 0 && t == 0) *sq = 0.f;

    // ---- 1. issue W global loads (10 float4/thread, latency overlapped below)
    float4 wr[10];
    {
        const float4* Wg = (const float4*)(W + (size_t)r0 * W_PER_R);
#pragma unroll
        for (int p = 0; p < 10; ++p) wr[p] = Wg[t + p * 256];
    }

    // ---- 2. c logits for rows r0..r0+7 (0 if nbuf==0 -> softmax = 0.1)
    if (t < 80) {
        float a = 0.f;
        int r_l = t / 10, d = t - r_l * 10;
        const float* p0 = ab + (size_t)(r0 + r_l) * DIGITS + d;
        for (int bu = 0; bu < nbuf; ++bu)
#pragma unroll
            for (int yy = 0; yy < YBLK; ++yy)
                a += p0[(size_t)bu * AB_STRIDE + (size_t)yy * (R_NODES * DIGITS)];
        cs[t] = a;
    }
    __syncthreads();
    if (t < 8) {
        float e[DIGITS];
        float m = -1e30f;
#pragma unroll
        for (int d = 0; d < DIGITS; ++d) m = fmaxf(m, cs[t*10 + d]);
        float ssum = 0.f;
#pragma unroll
        for (int d = 0; d < DIGITS; ++d) { e[d] = expf(cs[t*10 + d] - m); ssum += e[d]; }
        float inv = 1.f / ssum;
#pragma unroll
        for (int d = 0; d < DIGITS; ++d) cs[t*10 + d] = e[d] * inv;
    }
    __syncthreads();

    // ---- 3. scale by c and write to LDS (pad-stride 10; 2-way aliasing only)
#pragma unroll
    for (int p = 0; p < 10; ++p) {
        int e4 = t + p * 256;             // float4 index 0..2559 over 8 rows
        int e  = e4 * 4;
        int r_l = e4 / 320;               // 320 float4 per row
        int rem = e - r_l * W_PER_R;
        int col = rem >> 3, i0 = e & 7;   // i0 in {0,4}
        float cv = cs[r_l * 10 + (col >> 4)];
        float2* dst = (float2*)&wt[r_l * 1600 + col * 10 + i0];
        dst[0] = make_float2(wr[p].x * cv, wr[p].y * cv);
        dst[1] = make_float2(wr[p].z * cv, wr[p].w * cv);
    }
    __syncthreads();

    // ---- 4. compute: acc[jj][10] over 8 r-rows, u from global (L1)
    float acc[2][10];
#pragma unroll
    for (int jj = 0; jj < 2; ++jj)
#pragma unroll
        for (int j = 0; j < 10; ++j) acc[jj][j] = 0.f;

#pragma unroll 2
    for (int r_l = 0; r_l < 8; ++r_l) {
        float uu[2][8];
#pragma unroll
        for (int jj = 0; jj < 2; ++jj) {
            const float* up = u + (size_t)(b0 + bs*2 + jj) * (R_NODES*IN_CH)
                                + (size_t)(r0 + r_l) * IN_CH;
            float4 a0 = *(const float4*)up;
            float4 a1 = *(const float4*)(up + 4);
            uu[jj][0]=a0.x; uu[jj][1]=a0.y; uu[jj][2]=a0.z; uu[jj][3]=a0.w;
            uu[jj][4]=a1.x; uu[jj][5]=a1.y; uu[jj][6]=a1.z; uu[jj][7]=a1.w;
        }
        const float* wrow = &wt[r_l * 1600 + g * 100];
#pragma unroll
        for (int j = 0; j < 10; ++j) {
            const float2* wp = (const float2*)(wrow + j * 10);
            float2 w01 = wp[0], w23 = wp[1], w45 = wp[2], w67 = wp[3];
#pragma unroll
            for (int jj = 0; jj < 2; ++jj) {
                float a = acc[jj][j];
                a = fmaf(w01.x, uu[jj][0], a);
                a = fmaf(w01.y, uu[jj][1], a);
                a = fmaf(w23.x, uu[jj][2], a);
                a = fmaf(w23.y, uu[jj][3], a);
                a = fmaf(w45.x, uu[jj][4], a);
                a = fmaf(w45.y, uu[jj][5], a);
                a = fmaf(w67.x, uu[jj][6], a);
                a = fmaf(w67.y, uu[jj][7], a);
                acc[jj][j] = a;
            }
        }
    }

    // deterministic partial write (no atomics)
    float* pp = part + (size_t)split * (BATCH * COLS) + (size_t)b0 * COLS;
#pragma unroll
    for (int jj = 0; jj < 2; ++jj) {
        float* row = pp + (size_t)(bs*2 + jj) * COLS + g * 10;
#pragma unroll
        for (int j = 0; j < 10; ++j) row[j] = acc[jj][j];
    }
}

// ---------- reduce partials -> s ; accumulate global sum of squares ----------
// grid (640): 64 elements per block, 256 threads = 64 elems x 4-way split over
// the 144 partial buffers, LDS tree for the 4-way, wave-shuffle for sq.
__global__ void k_sq(const float* __restrict__ part,
                     float* __restrict__ s,
                     float* __restrict__ sq)
{
    const int t = threadIdx.x;
    const int e0 = blockIdx.x * 64;
    const int el = t & 63, q = t >> 6;
    float v = 0.f;
    for (int sp = q; sp < NSPLIT; sp += 4)
        v += part[(size_t)sp * (BATCH * COLS) + e0 + el];
    __shared__ float red[256];
    red[t] = v;
    __syncthreads();
    if (t < 64) {
        float vv = red[t] + red[t + 64] + red[t + 128] + red[t + 192];
        s[e0 + t] = vv;
        float x = vv * vv;
#pragma unroll
        for (int off = 32; off > 0; off >>= 1)
            x += __shfl_down(x, off, 64);
        if (t == 0) atomicAdd(sq, x);
    }
}

// ---------- agreement partials: ab[y][r,d] = scale * sum_{b in y,o} u_hat*s ----------
// grid (144, 8): 8 r-rows x 32 batches per block. 256 thr = 8 r_l x 32 lanes.
// s-tile [32][160] and u-tile [32][64] staged in LDS -> inner loop pure LDS+FMA.
__global__ __launch_bounds__(256) void k_a(
    const float* __restrict__ u,
    const float* __restrict__ W,
    const float* __restrict__ s,
    const float* __restrict__ sq,
    float* __restrict__ ab)
{
    __shared__ float st[32 * COLS];   // 20.5 KB
    __shared__ float ut[32 * 64];     // 8 KB
    const int t = threadIdx.x;
    const int rblk = blockIdx.x;
    const int r = rblk * 8 + (t >> 5);
    const int tt = t & 31;
    const int bstart = blockIdx.y * 32;

    {
        const float4* sp = (const float4*)(s + (size_t)bstart * COLS);
#pragma unroll
        for (int p = 0; p < 5; ++p) ((float4*)st)[t + p * 256] = sp[t + p * 256];
    }
#pragma unroll
    for (int p = 0; p < 2; ++p) {
        int idx = t + p * 256;
        int bb = idx >> 4, qq = idx & 15;
        ((float4*)ut)[idx] =
            ((const float4*)(u + (size_t)(bstart + bb) * (R_NODES*IN_CH) + (size_t)rblk * 64))[qq];
    }

    float wreg[5][8];
#pragma unroll
    for (int k = 0; k < 5; ++k) {
        const float4* wp = (const float4*)(W + (size_t)r * W_PER_R + (size_t)(tt + 32*k) * IN_CH);
        float4 w0 = wp[0], w1 = wp[1];
        wreg[k][0]=w0.x; wreg[k][1]=w0.y; wreg[k][2]=w0.z; wreg[k][3]=w0.w;
        wreg[k][4]=w1.x; wreg[k][5]=w1.y; wreg[k][6]=w1.z; wreg[k][7]=w1.w;
    }
    __syncthreads();

    float acc[5] = {0.f, 0.f, 0.f, 0.f, 0.f};
#pragma unroll 2
    for (int b = 0; b < 32; ++b) {
        const float* ub = &ut[b * 64 + (t >> 5) * 8];
        float4 a0 = *(const float4*)ub;
        float4 a1 = *(const float4*)(ub + 4);
        const float* sb = &st[b * COLS];
#pragma unroll
        for (int k = 0; k < 5; ++k) {
            float vv = sb[tt + 32*k];
            float uh;
            uh = wreg[k][0] * a0.x;
            uh = fmaf(wreg[k][1], a0.y, uh);
            uh = fmaf(wreg[k][2], a0.z, uh);
            uh = fmaf(wreg[k][3], a0.w, uh);
            uh = fmaf(wreg[k][4], a1.x, uh);
            uh = fmaf(wreg[k][5], a1.y, uh);
            uh = fmaf(wreg[k][6], a1.z, uh);
            uh = fmaf(wreg[k][7], a1.w, uh);
            acc[k] = fmaf(uh, vv, acc[k]);
        }
    }
    float q = *sq;
    float scale = sqrtf(q) / (1.f + q);
    float* abp = ab + (size_t)blockIdx.y * (R_NODES * DIGITS) + r * DIGITS;
#pragma unroll
    for (int k = 0; k < 5; ++k) {
        float x = acc[k] * scale;
        x += __shfl_xor(x, 1, 64);
        x += __shfl_xor(x, 2, 64);
        x += __shfl_xor(x, 4, 64);
        x += __shfl_xor(x, 8, 64);
        if ((tt & 15) == 0) {
            int d = (tt >> 4) + 2*k;
            abp[d] = x;
        }
    }
}

// ---------- final output: v = s * sqrt(sq)/(1+sq) ----------
__global__ void k_scale(const float* __restrict__ s,
                        const float* __restrict__ sq,
                        float* __restrict__ out)
{
    int e = blockIdx.x * 256 + threadIdx.x;
    float q = *sq;
    float scale = sqrtf(q) / (1.f + q);
    out[e] = s[e] * scale;
}

extern "C" void kernel_launch(void* const* d_in, const int* in_sizes, int n_in,
                              void* d_out, int out_size, void* d_ws, size_t ws_size,
                              hipStream_t stream)
{
    const float* u = (const float*)d_in[0];   // (256, 1152, 8)
    const float* W = (const float*)d_in[1];   // (1, 1152, 10, 16, 8)
    float* out = (float*)d_out;               // (256, 10, 16)
    float* ws = (float*)d_ws;

    float* s    = ws;                          // 40960 floats
    float* sq   = ws + 40960;                  // 1 (padded to 64)
    float* ab   = ws + 41024;                  // 2 * 92160
    float* part = ws + 41024 + 2 * AB_STRIDE;  // 144 * 40960 (~23.6 MB; ws is 256 MiB)

    for (int it = 0; it < 3; ++it) {
        k_s<<<dim3(NSPLIT, YB_S), dim3(256), 0, stream>>>(u, W, ab, part, sq, it);
        k_sq<<<dim3(BATCH * COLS / 64), dim3(256), 0, stream>>>(part, s, sq);
        if (it < 2)
            k_a<<<dim3(R_NODES / 8, YBLK), dim3(256), 0, stream>>>(u, W, s, sq,
                                                                   ab + (size_t)it * AB_STRIDE);
        else
            k_scale<<<dim3(BATCH * COLS / 256), dim3(256), 0, stream>>>(s, sq, out);
    }
}

// Round 7
// 165.218 us; speedup vs baseline: 1.3659x; 1.0063x over previous
//
#include <hip/hip_runtime.h>
#include <math.h>

#define R_NODES 1152
#define DIGITS 10
#define OUT_CH 16
#define IN_CH 8
#define BATCH 256
#define COLS 160            // DIGITS*OUT_CH
#define W_PER_R 1280        // DIGITS*OUT_CH*IN_CH
#define NSPLIT 144          // K-split: 8 r-rows per block
#define YB_S 4              // k_s batch blocks (64 b each)
#define YBLK 8              // k_a batch blocks (32 b each)
#define SGRP 102            // LDS colgroup stride: 102%32=6 -> g*6 mod 32 distinct for g=0..15
#define SROW (16 * SGRP)    // 1632 floats per r-row
#define AB_STRIDE (YBLK * R_NODES * DIGITS)   // 92160 floats per ab iteration-buffer

// ---------- s partials + fused per-block softmax ----------
// grid (144, 4): blockIdx.x = 8-row slice, blockIdx.y = 64-batch block.
// 256 threads = 16 colgroups (g, 10 cols each) x 16 batch-quads (bs, jj=4).
// W for all 8 rows staged once into 52.2 KB LDS with conflict-free swizzle:
// column c lives at (c/10)*102 + (c%10)*10, so the 16 g-lanes' float2 reads
// hit 16 distinct even bank-starts (g*6 mod 32) covering all 32 banks.
// jj=4 doubles FMA per LDS byte vs r6 -> LDS and VALU pipes balanced.
__global__ __launch_bounds__(256) void k_s(
    const float* __restrict__ u,      // [B][R][8]
    const float* __restrict__ W,      // [R][10][16][8]
    const float* __restrict__ ab,     // [nbuf][YBLK][R][10] agreement partials
    float* __restrict__ part,         // [NSPLIT][B][160]
    float* __restrict__ sq,
    int nbuf)
{
    __shared__ float wt[8 * SROW];      // 52,224 B
    __shared__ float cs[80];            // c for this block's 8 rows

    const int split = blockIdx.x;
    const int b0 = blockIdx.y * 64;
    const int t = threadIdx.x;
    const int g = t & 15;
    const int bs = t >> 4;
    const int r0 = split * 8;

    if (split == 0 && blockIdx.y == 0 && t == 0) *sq = 0.f;

    // ---- 1. issue W global loads (10 float4/thread, latency overlapped below)
    float4 wr[10];
    {
        const float4* Wg = (const float4*)(W + (size_t)r0 * W_PER_R);
#pragma unroll
        for (int p = 0; p < 10; ++p) wr[p] = Wg[t + p * 256];
    }

    // ---- 2. c logits for rows r0..r0+7 (0 if nbuf==0 -> softmax = 0.1)
    if (t < 80) {
        float a = 0.f;
        int r_l = t / 10, d = t - r_l * 10;
        const float* p0 = ab + (size_t)(r0 + r_l) * DIGITS + d;
        for (int bu = 0; bu < nbuf; ++bu)
#pragma unroll
            for (int yy = 0; yy < YBLK; ++yy)
                a += p0[(size_t)bu * AB_STRIDE + (size_t)yy * (R_NODES * DIGITS)];
        cs[t] = a;
    }
    __syncthreads();
    if (t < 8) {
        float e[DIGITS];
        float m = -1e30f;
#pragma unroll
        for (int d = 0; d < DIGITS; ++d) m = fmaxf(m, cs[t*10 + d]);
        float ssum = 0.f;
#pragma unroll
        for (int d = 0; d < DIGITS; ++d) { e[d] = expf(cs[t*10 + d] - m); ssum += e[d]; }
        float inv = 1.f / ssum;
#pragma unroll
        for (int d = 0; d < DIGITS; ++d) cs[t*10 + d] = e[d] * inv;
    }
    __syncthreads();

    // ---- 3. scale by c and write to swizzled LDS
#pragma unroll
    for (int p = 0; p < 10; ++p) {
        int e4 = t + p * 256;             // float4 index 0..2559 over 8 rows
        int e  = e4 * 4;
        int r_l = e4 / 320;               // 320 float4 per row
        int rem = e - r_l * W_PER_R;
        int col = rem >> 3, i0 = e & 7;   // i0 in {0,4}
        int cg = col / 10, cj = col - cg * 10;
        float cv = cs[r_l * 10 + (col >> 4)];
        float2* dst = (float2*)&wt[r_l * SROW + cg * SGRP + cj * 10 + i0];
        dst[0] = make_float2(wr[p].x * cv, wr[p].y * cv);
        dst[1] = make_float2(wr[p].z * cv, wr[p].w * cv);
    }
    __syncthreads();

    // ---- 4. compute: acc[jj][10] over 8 r-rows, u from global (L1)
    float acc[4][10];
#pragma unroll
    for (int jj = 0; jj < 4; ++jj)
#pragma unroll
        for (int j = 0; j < 10; ++j) acc[jj][j] = 0.f;

#pragma unroll 2
    for (int r_l = 0; r_l < 8; ++r_l) {
        float uu[4][8];
#pragma unroll
        for (int jj = 0; jj < 4; ++jj) {
            const float* up = u + (size_t)(b0 + bs*4 + jj) * (R_NODES*IN_CH)
                                + (size_t)(r0 + r_l) * IN_CH;
            float4 a0 = *(const float4*)up;
            float4 a1 = *(const float4*)(up + 4);
            uu[jj][0]=a0.x; uu[jj][1]=a0.y; uu[jj][2]=a0.z; uu[jj][3]=a0.w;
            uu[jj][4]=a1.x; uu[jj][5]=a1.y; uu[jj][6]=a1.z; uu[jj][7]=a1.w;
        }
        const float* wrow = &wt[r_l * SROW + g * SGRP];
#pragma unroll
        for (int j = 0; j < 10; ++j) {
            const float2* wp = (const float2*)(wrow + j * 10);
            float2 w01 = wp[0], w23 = wp[1], w45 = wp[2], w67 = wp[3];
#pragma unroll
            for (int jj = 0; jj < 4; ++jj) {
                float a = acc[jj][j];
                a = fmaf(w01.x, uu[jj][0], a);
                a = fmaf(w01.y, uu[jj][1], a);
                a = fmaf(w23.x, uu[jj][2], a);
                a = fmaf(w23.y, uu[jj][3], a);
                a = fmaf(w45.x, uu[jj][4], a);
                a = fmaf(w45.y, uu[jj][5], a);
                a = fmaf(w67.x, uu[jj][6], a);
                a = fmaf(w67.y, uu[jj][7], a);
                acc[jj][j] = a;
            }
        }
    }

    // deterministic partial write (no atomics)
    float* pp = part + (size_t)split * (BATCH * COLS) + (size_t)b0 * COLS;
#pragma unroll
    for (int jj = 0; jj < 4; ++jj) {
        float* row = pp + (size_t)(bs*4 + jj) * COLS + g * 10;
#pragma unroll
        for (int j = 0; j < 10; ++j) row[j] = acc[jj][j];
    }
}

// ---------- reduce partials -> s ; accumulate global sum of squares ----------
// grid (640): 64 elements per block, 256 threads = 64 elems x 4-way split over
// the 144 partial buffers, LDS tree for the 4-way, wave-shuffle for sq.
__global__ void k_sq(const float* __restrict__ part,
                     float* __restrict__ s,
                     float* __restrict__ sq)
{
    const int t = threadIdx.x;
    const int e0 = blockIdx.x * 64;
    const int el = t & 63, q = t >> 6;
    float v = 0.f;
    for (int sp = q; sp < NSPLIT; sp += 4)
        v += part[(size_t)sp * (BATCH * COLS) + e0 + el];
    __shared__ float red[256];
    red[t] = v;
    __syncthreads();
    if (t < 64) {
        float vv = red[t] + red[t + 64] + red[t + 128] + red[t + 192];
        s[e0 + t] = vv;
        float x = vv * vv;
#pragma unroll
        for (int off = 32; off > 0; off >>= 1)
            x += __shfl_down(x, off, 64);
        if (t == 0) atomicAdd(sq, x);
    }
}

// ---------- agreement partials: ab[y][r,d] = scale * sum_{b in y,o} u_hat*s ----------
// grid (144, 8): 8 r-rows x 32 batches per block. 256 thr = 8 r_l x 32 lanes.
// s-tile [32][160] and u-tile [32][64] staged in LDS -> inner loop pure LDS+FMA.
__global__ __launch_bounds__(256) void k_a(
    const float* __restrict__ u,
    const float* __restrict__ W,
    const float* __restrict__ s,
    const float* __restrict__ sq,
    float* __restrict__ ab)
{
    __shared__ float st[32 * COLS];   // 20.5 KB
    __shared__ float ut[32 * 64];     // 8 KB
    const int t = threadIdx.x;
    const int rblk = blockIdx.x;
    const int r = rblk * 8 + (t >> 5);
    const int tt = t & 31;
    const int bstart = blockIdx.y * 32;

    {
        const float4* sp = (const float4*)(s + (size_t)bstart * COLS);
#pragma unroll
        for (int p = 0; p < 5; ++p) ((float4*)st)[t + p * 256] = sp[t + p * 256];
    }
#pragma unroll
    for (int p = 0; p < 2; ++p) {
        int idx = t + p * 256;
        int bb = idx >> 4, qq = idx & 15;
        ((float4*)ut)[idx] =
            ((const float4*)(u + (size_t)(bstart + bb) * (R_NODES*IN_CH) + (size_t)rblk * 64))[qq];
    }

    float wreg[5][8];
#pragma unroll
    for (int k = 0; k < 5; ++k) {
        const float4* wp = (const float4*)(W + (size_t)r * W_PER_R + (size_t)(tt + 32*k) * IN_CH);
        float4 w0 = wp[0], w1 = wp[1];
        wreg[k][0]=w0.x; wreg[k][1]=w0.y; wreg[k][2]=w0.z; wreg[k][3]=w0.w;
        wreg[k][4]=w1.x; wreg[k][5]=w1.y; wreg[k][6]=w1.z; wreg[k][7]=w1.w;
    }
    __syncthreads();

    float acc[5] = {0.f, 0.f, 0.f, 0.f, 0.f};
#pragma unroll 2
    for (int b = 0; b < 32; ++b) {
        const float* ub = &ut[b * 64 + (t >> 5) * 8];
        float4 a0 = *(const float4*)ub;
        float4 a1 = *(const float4*)(ub + 4);
        const float* sb = &st[b * COLS];
#pragma unroll
        for (int k = 0; k < 5; ++k) {
            float vv = sb[tt + 32*k];
            float uh;
            uh = wreg[k][0] * a0.x;
            uh = fmaf(wreg[k][1], a0.y, uh);
            uh = fmaf(wreg[k][2], a0.z, uh);
            uh = fmaf(wreg[k][3], a0.w, uh);
            uh = fmaf(wreg[k][4], a1.x, uh);
            uh = fmaf(wreg[k][5], a1.y, uh);
            uh = fmaf(wreg[k][6], a1.z, uh);
            uh = fmaf(wreg[k][7], a1.w, uh);
            acc[k] = fmaf(uh, vv, acc[k]);
        }
    }
    float q = *sq;
    float scale = sqrtf(q) / (1.f + q);
    float* abp = ab + (size_t)blockIdx.y * (R_NODES * DIGITS) + r * DIGITS;
#pragma unroll
    for (int k = 0; k < 5; ++k) {
        float x = acc[k] * scale;
        x += __shfl_xor(x, 1, 64);
        x += __shfl_xor(x, 2, 64);
        x += __shfl_xor(x, 4, 64);
        x += __shfl_xor(x, 8, 64);
        if ((tt & 15) == 0) {
            int d = (tt >> 4) + 2*k;
            abp[d] = x;
        }
    }
}

// ---------- final output: v = s * sqrt(sq)/(1+sq) ----------
__global__ void k_scale(const float* __restrict__ s,
                        const float* __restrict__ sq,
                        float* __restrict__ out)
{
    int e = blockIdx.x * 256 + threadIdx.x;
    float q = *sq;
    float scale = sqrtf(q) / (1.f + q);
    out[e] = s[e] * scale;
}

extern "C" void kernel_launch(void* const* d_in, const int* in_sizes, int n_in,
                              void* d_out, int out_size, void* d_ws, size_t ws_size,
                              hipStream_t stream)
{
    const float* u = (const float*)d_in[0];   // (256, 1152, 8)
    const float* W = (const float*)d_in[1];   // (1, 1152, 10, 16, 8)
    float* out = (float*)d_out;               // (256, 10, 16)
    float* ws = (float*)d_ws;

    float* s    = ws;                          // 40960 floats
    float* sq   = ws + 40960;                  // 1 (padded to 64)
    float* ab   = ws + 41024;                  // 2 * 92160
    float* part = ws + 41024 + 2 * AB_STRIDE;  // 144 * 40960 (~23.6 MB; ws is 256 MiB)

    for (int it = 0; it < 3; ++it) {
        k_s<<<dim3(NSPLIT, YB_S), dim3(256), 0, stream>>>(u, W, ab, part, sq, it);
        k_sq<<<dim3(BATCH * COLS / 64), dim3(256), 0, stream>>>(part, s, sq);
        if (it < 2)
            k_a<<<dim3(R_NODES / 8, YBLK), dim3(256), 0, stream>>>(u, W, s, sq,
                                                                   ab + (size_t)it * AB_STRIDE);
        else
            k_scale<<<dim3(BATCH * COLS / 256), dim3(256), 0, stream>>>(s, sq, out);
    }
}